// Round 10
// baseline (90.405 us; speedup 1.0000x reference)
//
#include <hip/hip_runtime.h>
#include <hip/hip_bf16.h>

#define S_ 8192
#define H_ 8
#define D_ 64
#define M_ 64
#define BH_ 32
#define CPK_ 80          // buf1/partial row stride (c 0..79, den at c=64)
#define MC_ (M_ * CPK_)
#define NCHQ 16
#define TILE 64
#define QTILES (S_ / NCHQ / TILE)   // 8

typedef short bf16x8 __attribute__((ext_vector_type(8)));
typedef float f32x4 __attribute__((ext_vector_type(4)));

constexpr float XS_ = 0.35355339059327373f * 1.4426950408889634f; // D^-1/4 * log2(e)
constexpr float HS_ = 0.34657359027997264f;                        // ln2/2
constexpr float EPS_ = 1e-6f;

__device__ __forceinline__ unsigned short f2bf(float f) {
    unsigned int u = __float_as_uint(f);
    u += 0x7FFFu + ((u >> 16) & 1u);          // RNE
    return (unsigned short)(u >> 16);
}
__device__ __forceinline__ unsigned int pkbf(float lo, float hi) {
    __hip_bfloat162 t = __float22bfloat162_rn(float2{lo, hi});
    return *reinterpret_cast<unsigned int*>(&t);
}
__device__ __forceinline__ float fexp2(float x) { return __builtin_amdgcn_exp2f(x); }

#define MFMA(a, b, c) __builtin_amdgcn_mfma_f32_16x16x32_bf16((a), (b), (c), 0, 0, 0)
#define SWZ(byteoff, row) ((byteoff) ^ (((row) & 7) << 4))

#define GLDS(src, dst) __builtin_amdgcn_global_load_lds( \
    (const __attribute__((address_space(1))) void*)(src), \
    (__attribute__((address_space(3))) void*)(dst), 16, 0, 0)

// ---------------------------------------------------------------------------
// Phase K — SPILL-PROOF rewrite. Diagnosis r3-r9: prefetch/acc state passed
// through lambda pointer params + register demand > reported VGPR count =>
// compiler spilled the pipeline to scratch; every "prefetch" was a scratch
// round-trip (all pipes idle, ~60us invariant). Here: single-wave blocks,
// all hot state in straight-line macro code (no pointer escapes), GLDS
// staging (2x8KB bufs), counted vmcnt(8) waits (never 0 mid-loop) +
// sched_barrier. Index math verbatim from r9 (correctness-verified).
// ---------------------------------------------------------------------------
__global__ void __launch_bounds__(64, 2)
fa_k(const float* __restrict__ ks, const float* __restrict__ vs,
     const float* __restrict__ proj, float* __restrict__ partial,
     int nch, int segs)
{
    __shared__ __align__(16) char bufA[8192];   // k 4KB | v 4KB
    __shared__ __align__(16) char bufB[8192];

    const int chunk = blockIdx.x;
    const int bh    = blockIdx.y;
    const int b = bh >> 3, h = bh & 7;
    const int lane = threadIdx.x & 63;
    const int l15 = lane & 15, g = lane >> 4;

    const size_t rs = (size_t)H_ * D_;
    const float* kb = ks + ((size_t)b * S_ * H_ + h) * D_;
    const float* vb = vs + ((size_t)b * S_ * H_ + h) * D_;

    // proj B-fragments (r9-verified): m = mt*16+l15, d = g*8+j (+32*kk)
    bf16x8 pf[4][2];
#pragma unroll
    for (int mt = 0; mt < 4; ++mt)
#pragma unroll
        for (int kk = 0; kk < 2; ++kk) {
            const float* p = proj + (mt * 16 + l15) * D_ + kk * 32 + g * 8;
            float4 a = *(const float4*)p, c = *(const float4*)(p + 4);
            union { bf16x8 v; unsigned int u[4]; } F;
            F.u[0] = pkbf(a.x, a.y); F.u[1] = pkbf(a.z, a.w);
            F.u[2] = pkbf(c.x, c.y); F.u[3] = pkbf(c.z, c.w);
            pf[mt][kk] = F.v;
        }

    bf16x8 onef = {0, 0, 0, 0, 0, 0, 0, 0};
    if (l15 == 0) {
#pragma unroll
        for (int j = 0; j < 8; ++j) onef[j] = (short)0x3F80;
    }

    f32x4 acc[4][5];
#pragma unroll
    for (int mt = 0; mt < 4; ++mt)
#pragma unroll
        for (int ci = 0; ci < 5; ++ci) acc[mt][ci] = (f32x4){0.f, 0.f, 0.f, 0.f};

    f32x4 paE[4], paO[4];
    float hrE[4], hrO[4];
    unsigned int vbu[4][4];   // per-ct EV B-frag words (constant-indexed only)

// issue 8 DMA ops for tile T into BUF (k->BUF, v->BUF+4096); dst wave-uniform
#define STAGE(T, BUF) do {                                                  \
    const float* krow_ = kb + (size_t)(rbase + (T) * 16 + l15) * rs;        \
    const float* vrow_ = vb + (size_t)(rbase + (T) * 16 + l15) * rs;        \
    _Pragma("unroll")                                                       \
    for (int i_ = 0; i_ < 4; ++i_) {                                        \
        int c0_ = (i_ >> 1) * 32 + (i_ & 1) * 4 + 8 * g;                    \
        GLDS(krow_ + c0_, (BUF) + i_ * 1024);                               \
        GLDS(vrow_ + c0_, (BUF) + 4096 + i_ * 1024);                        \
    } } while (0)

// k of BUF -> P fragments PA[0..3], row-h HR[0..3]  (r9-verified math)
#define CONSUME(BUF, PA, HR) do {                                           \
    f32x4 r0_ = *(const f32x4*)((BUF) + lane * 16);                         \
    f32x4 r1_ = *(const f32x4*)((BUF) + 1024 + lane * 16);                  \
    f32x4 r2_ = *(const f32x4*)((BUF) + 2048 + lane * 16);                  \
    f32x4 r3_ = *(const f32x4*)((BUF) + 3072 + lane * 16);                  \
    float kx_[16];                                                          \
    _Pragma("unroll")                                                       \
    for (int j_ = 0; j_ < 4; ++j_) {                                        \
        kx_[j_]      = r0_[j_] * XS_;  kx_[4 + j_]  = r1_[j_] * XS_;        \
        kx_[8 + j_]  = r2_[j_] * XS_;  kx_[12 + j_] = r3_[j_] * XS_;        \
    }                                                                       \
    float sq_ = 0.f;                                                        \
    _Pragma("unroll")                                                       \
    for (int j_ = 0; j_ < 16; ++j_) sq_ += kx_[j_] * kx_[j_];               \
    sq_ += __shfl_xor(sq_, 16);                                             \
    sq_ += __shfl_xor(sq_, 32);                                             \
    float hrow_ = sq_ * HS_ + 3.0f;                                         \
    union { bf16x8 v; unsigned int u[4]; } A0_, A1_;                        \
    _Pragma("unroll")                                                       \
    for (int i_ = 0; i_ < 4; ++i_) {                                        \
        A0_.u[i_] = pkbf(kx_[2 * i_], kx_[2 * i_ + 1]);                     \
        A1_.u[i_] = pkbf(kx_[8 + 2 * i_], kx_[9 + 2 * i_]);                 \
    }                                                                       \
    _Pragma("unroll")                                                       \
    for (int mt_ = 0; mt_ < 4; ++mt_) {                                     \
        PA[mt_] = (f32x4){0.f, 0.f, 0.f, 0.f};                              \
        PA[mt_] = MFMA(A0_.v, pf[mt_][0], PA[mt_]);                         \
        PA[mt_] = MFMA(A1_.v, pf[mt_][1], PA[mt_]);                         \
    }                                                                       \
    _Pragma("unroll")                                                       \
    for (int r_ = 0; r_ < 4; ++r_) HR[r_] = __shfl(hrow_, 4 * g + r_);      \
    } while (0)

// v of BUF -> half of the EV B-frag words (I0,I1 = 0,1 for even / 2,3 odd)
#define VHALF(BUF, I0, I1) do {                                             \
    const char* vd_ = (BUF) + 4096;                                         \
    _Pragma("unroll")                                                       \
    for (int ct_ = 0; ct_ < 4; ++ct_) {                                     \
        int c_ = ct_ * 16 + l15;                                            \
        int ic_ = ((c_ >> 5) << 1) | ((c_ >> 2) & 1);                       \
        int boff_ = ic_ * 1024 + ((c_ & 31) >> 3) * 256 + (c_ & 3) * 4      \
                  + 64 * g;                                                 \
        float e0_ = *(const float*)(vd_ + boff_);                           \
        float e1_ = *(const float*)(vd_ + boff_ + 16);                      \
        float e2_ = *(const float*)(vd_ + boff_ + 32);                      \
        float e3_ = *(const float*)(vd_ + boff_ + 48);                      \
        vbu[ct_][I0] = pkbf(e0_, e1_);                                      \
        vbu[ct_][I1] = pkbf(e2_, e3_);                                      \
    } } while (0)

// pure-register EV: build E (sigma A-layout, r9-verified) and 20 MFMAs
#define EVREG() do {                                                        \
    _Pragma("unroll")                                                       \
    for (int mt_ = 0; mt_ < 4; ++mt_) {                                     \
        union { bf16x8 v; unsigned int u[4]; } E_;                          \
        E_.u[0] = pkbf(fexp2(paE[mt_][0] - hrE[0]),                         \
                       fexp2(paE[mt_][1] - hrE[1]));                        \
        E_.u[1] = pkbf(fexp2(paE[mt_][2] - hrE[2]),                         \
                       fexp2(paE[mt_][3] - hrE[3]));                        \
        E_.u[2] = pkbf(fexp2(paO[mt_][0] - hrO[0]),                         \
                       fexp2(paO[mt_][1] - hrO[1]));                        \
        E_.u[3] = pkbf(fexp2(paO[mt_][2] - hrO[2]),                         \
                       fexp2(paO[mt_][3] - hrO[3]));                        \
        _Pragma("unroll")                                                   \
        for (int ct_ = 0; ct_ < 4; ++ct_) {                                 \
            union { bf16x8 v; unsigned int u[4]; } B_;                      \
            B_.u[0] = vbu[ct_][0]; B_.u[1] = vbu[ct_][1];                   \
            B_.u[2] = vbu[ct_][2]; B_.u[3] = vbu[ct_][3];                   \
            acc[mt_][ct_] = MFMA(E_.v, B_.v, acc[mt_][ct_]);                \
        }                                                                   \
        acc[mt_][4] = MFMA(E_.v, onef, acc[mt_][4]);                        \
    } } while (0)

#define WAIT8 do { asm volatile("s_waitcnt vmcnt(8)" ::: "memory");         \
                   __builtin_amdgcn_sched_barrier(0); } while (0)
#define WAIT0 do { asm volatile("s_waitcnt vmcnt(0)" ::: "memory");         \
                   __builtin_amdgcn_sched_barrier(0); } while (0)

    for (int seg = 0; seg < segs; ++seg) {
        const int rbase = (chunk * segs + seg) * 128;

        STAGE(0, bufA); STAGE(1, bufB);                   // 16 in flight

        WAIT8; CONSUME(bufA, paE, hrE); VHALF(bufA, 0, 1); STAGE(2, bufA);
        WAIT8; CONSUME(bufB, paO, hrO); VHALF(bufB, 2, 3); STAGE(3, bufB);
        EVREG();

        WAIT8; CONSUME(bufA, paE, hrE); VHALF(bufA, 0, 1); STAGE(4, bufA);
        WAIT8; CONSUME(bufB, paO, hrO); VHALF(bufB, 2, 3); STAGE(5, bufB);
        EVREG();

        WAIT8; CONSUME(bufA, paE, hrE); VHALF(bufA, 0, 1); STAGE(6, bufA);
        WAIT8; CONSUME(bufB, paO, hrO); VHALF(bufB, 2, 3); STAGE(7, bufB);
        EVREG();

        WAIT8; CONSUME(bufA, paE, hrE); VHALF(bufA, 0, 1);
        WAIT0; CONSUME(bufB, paO, hrO); VHALF(bufB, 2, 3);
        EVREG();
    }

    // single wave owns the full 64x80 partial: direct store, no reduce
    float* dst = partial + ((size_t)bh * nch + chunk) * MC_;
#pragma unroll
    for (int mt = 0; mt < 4; ++mt)
#pragma unroll
        for (int ct = 0; ct < 5; ++ct)
#pragma unroll
            for (int r = 0; r < 4; ++r)
                dst[(mt * 16 + 4 * g + r) * CPK_ + ct * 16 + l15] =
                    acc[mt][ct][r];
}

// ---------------------------------------------------------------------------
// Reduce partials over chunks -> buf1[bh][m][CPK_]
// ---------------------------------------------------------------------------
__global__ void __launch_bounds__(256)
fa_r(const float* __restrict__ partial, float* __restrict__ buf1, int nch)
{
    int e = blockIdx.x * 256 + threadIdx.x;
    if (e >= BH_ * MC_) return;
    int bh = e / MC_;
    int r  = e - bh * MC_;
    const float* src = partial + (size_t)bh * nch * MC_ + r;
    float s0 = 0.f, s1 = 0.f, s2 = 0.f, s3 = 0.f;
    int ch = 0;
    for (; ch + 4 <= nch; ch += 4) {
        s0 += src[(size_t)(ch + 0) * MC_];
        s1 += src[(size_t)(ch + 1) * MC_];
        s2 += src[(size_t)(ch + 2) * MC_];
        s3 += src[(size_t)(ch + 3) * MC_];
    }
    for (; ch < nch; ++ch) s0 += src[(size_t)ch * MC_];
    buf1[e] = (s0 + s1) + (s2 + s3);
}

// ---------------------------------------------------------------------------
// Phase Q: unchanged (fast, ~10us). P = mfma(Qscaled, projT); e = exp2(P-h);
// D[c][qrow] = mfma(buf1T, E_T); den = row c=64; out = num/den.
// ---------------------------------------------------------------------------
__global__ void __launch_bounds__(256)
fa_q(const float* __restrict__ qs, const float* __restrict__ proj,
     const float* __restrict__ buf1, float* __restrict__ out)
{
    const int chunk = blockIdx.x;
    const int bh    = blockIdx.y;
    const int b = bh >> 3, h = bh & 7;
    const int tid = threadIdx.x, wid = tid >> 6, lane = tid & 63;
    const int l15 = lane & 15, g = lane >> 4;

    __shared__ __align__(16) char eLb[2][TILE * M_ * 2];
    __shared__ __align__(16) char b1tb[CPK_ * M_ * 2];

    const int rows = S_ / NCHQ;
    const int s0 = chunk * rows;
    const size_t rs = (size_t)H_ * D_;
    const float* qb = qs + ((size_t)b * S_ * H_ + h) * D_;

    const float* b1 = buf1 + (size_t)bh * MC_;
    for (int i = tid; i < MC_; i += 256) {
        int m = i / CPK_, c = i - m * CPK_;
        *(unsigned short*)(b1tb + SWZ(c * 128 + 2 * m, c)) = f2bf(b1[i]);
    }

    bf16x8 pf[4][2];
#pragma unroll
    for (int mt = 0; mt < 4; ++mt)
#pragma unroll
        for (int kk = 0; kk < 2; ++kk) {
            const float* p = proj + (mt * 16 + l15) * D_ + kk * 32 + g * 8;
            float4 a = *(const float4*)p, c = *(const float4*)(p + 4);
            union { bf16x8 v; unsigned int u[4]; } F;
            F.u[0] = pkbf(a.x, a.y); F.u[1] = pkbf(a.z, a.w);
            F.u[2] = pkbf(c.x, c.y); F.u[3] = pkbf(c.z, c.w);
            pf[mt][kk] = F.v;
        }
    __syncthreads();

    bf16x8 af3[5][2];
#pragma unroll
    for (int ci = 0; ci < 5; ++ci)
#pragma unroll
        for (int kk = 0; kk < 2; ++kk) {
            int c = ci * 16 + l15;
            af3[ci][kk] = *(const bf16x8*)(b1tb + SWZ(c * 128 + 16 * g + 64 * kk, c));
        }

    auto loadQ = [&](int t, float4* qp) {
        int sb = s0 + t * TILE;
        const float* qrow = qb + (size_t)(sb + wid * 16 + l15) * rs;
        qp[0] = *(const float4*)(qrow + g * 8);
        qp[1] = *(const float4*)(qrow + g * 8 + 4);
        qp[2] = *(const float4*)(qrow + 32 + g * 8);
        qp[3] = *(const float4*)(qrow + 32 + g * 8 + 4);
    };

    auto body = [&](int t, int p, const float4* qc, float4* qn) {
        if (t + 1 < QTILES) loadQ(t + 1, qn);

        float kx[16];
#pragma unroll
        for (int i = 0; i < 4; ++i) {
            kx[4 * i + 0] = qc[i].x * XS_; kx[4 * i + 1] = qc[i].y * XS_;
            kx[4 * i + 2] = qc[i].z * XS_; kx[4 * i + 3] = qc[i].w * XS_;
        }
        float sq = 0.f;
#pragma unroll
        for (int j = 0; j < 16; ++j) sq += kx[j] * kx[j];
        sq += __shfl_xor(sq, 16);
        sq += __shfl_xor(sq, 32);
        float hrow = sq * HS_ + 3.0f;

        union { bf16x8 v; unsigned int u[4]; } A0, A1;
#pragma unroll
        for (int i = 0; i < 4; ++i) {
            A0.u[i] = pkbf(kx[2 * i], kx[2 * i + 1]);
            A1.u[i] = pkbf(kx[8 + 2 * i], kx[9 + 2 * i]);
        }

        f32x4 pa[4];
#pragma unroll
        for (int mt = 0; mt < 4; ++mt) {
            pa[mt] = (f32x4){0.f, 0.f, 0.f, 0.f};
            pa[mt] = MFMA(A0.v, pf[mt][0], pa[mt]);
            pa[mt] = MFMA(A1.v, pf[mt][1], pa[mt]);
        }

        float hr[4];
#pragma unroll
        for (int r = 0; r < 4; ++r) hr[r] = __shfl(hrow, 4 * g + r);

        char* elp = eLb[p];
#pragma unroll
        for (int mt = 0; mt < 4; ++mt) {
            int m = mt * 16 + l15;
            float e0 = fexp2(pa[mt][0] - hr[0]);
            float e1 = fexp2(pa[mt][1] - hr[1]);
            float e2 = fexp2(pa[mt][2] - hr[2]);
            float e3 = fexp2(pa[mt][3] - hr[3]);
            unsigned int p01 = pkbf(e0, e1), p23 = pkbf(e2, e3);
            int q0 = wid * 16 + 4 * g;
            *(unsigned short*)(elp + SWZ((q0 + 0) * 128 + 2 * m, q0 + 0)) =
                (unsigned short)p01;
            *(unsigned short*)(elp + SWZ((q0 + 1) * 128 + 2 * m, q0 + 1)) =
                (unsigned short)(p01 >> 16);
            *(unsigned short*)(elp + SWZ((q0 + 2) * 128 + 2 * m, q0 + 2)) =
                (unsigned short)p23;
            *(unsigned short*)(elp + SWZ((q0 + 3) * 128 + 2 * m, q0 + 3)) =
                (unsigned short)(p23 >> 16);
        }
        __syncthreads();

        bf16x8 b3[2];
        {
            int qrow = wid * 16 + l15;
            b3[0] = *(const bf16x8*)(elp + SWZ(qrow * 128 + 16 * g, qrow));
            b3[1] = *(const bf16x8*)(elp + SWZ(qrow * 128 + 16 * g + 64, qrow));
        }
        f32x4 dt[5];
#pragma unroll
        for (int ci = 0; ci < 5; ++ci) {
            dt[ci] = (f32x4){0.f, 0.f, 0.f, 0.f};
            dt[ci] = MFMA(af3[ci][0], b3[0], dt[ci]);
            dt[ci] = MFMA(af3[ci][1], b3[1], dt[ci]);
        }

        float den = __shfl(dt[4][0], l15);
        float rd = 1.0f / fmaxf(den, EPS_);

        int sg = s0 + t * TILE + wid * 16 + l15;
        size_t base = (((size_t)b * S_ + sg) * H_ + h) * D_;
#pragma unroll
        for (int ci = 0; ci < 4; ++ci) {
            f32x4 o;
#pragma unroll
            for (int r = 0; r < 4; ++r) o[r] = dt[ci][r] * rd;
            *(f32x4*)(out + base + ci * 16 + 4 * g) = o;
        }
    };

    float4 qa[4], qb2[4];
    loadQ(0, qa);
    for (int t = 0; t < QTILES; t += 2) {
        body(t, 0, qa, qb2);
        body(t + 1, 1, qb2, qa);
    }
}

extern "C" void kernel_launch(void* const* d_in, const int* in_sizes, int n_in,
                              void* d_out, int out_size, void* d_ws, size_t ws_size,
                              hipStream_t stream)
{
    const float* qs   = (const float*)d_in[0];
    const float* ks   = (const float*)d_in[1];
    const float* vs   = (const float*)d_in[2];
    const float* proj = (const float*)d_in[3];
    float* out = (float*)d_out;

    // prefer 64 chunks (2048 single-wave blocks, 8/CU); fall back if ws tight
    int nch = 64, segs = 1;
    if ((size_t)BH_ * (size_t)(nch + 1) * MC_ * sizeof(float) > ws_size) {
        nch = 32; segs = 2;
    }

    float* partial = (float*)d_ws;                // BH*nch*MC_
    float* buf1 = partial + (size_t)BH_ * nch * MC_;

    fa_k<<<dim3(nch, BH_), 64, 0, stream>>>(ks, vs, proj, partial, nch, segs);
    int nred = (BH_ * MC_ + 255) / 256;
    fa_r<<<dim3(nred), 256, 0, stream>>>(partial, buf1, nch);
    fa_q<<<dim3(NCHQ, BH_), 256, 0, stream>>>(qs, proj, buf1, out);
}

// Round 11
// 83.747 us; speedup vs baseline: 1.0795x; 1.0795x over previous
//
#include <hip/hip_runtime.h>
#include <hip/hip_bf16.h>

#define S_ 8192
#define H_ 8
#define D_ 64
#define M_ 64
#define BH_ 32
#define CPK_ 80          // buf1/partial row stride (c 0..79, den at c=64)
#define MC_ (M_ * CPK_)
#define NCHQ 16
#define TILE 64
#define QTILES (S_ / NCHQ / TILE)   // 8

typedef short bf16x8 __attribute__((ext_vector_type(8)));
typedef float f32x4 __attribute__((ext_vector_type(4)));

constexpr float XS_ = 0.35355339059327373f * 1.4426950408889634f; // D^-1/4 * log2(e)
constexpr float HS_ = 0.34657359027997264f;                        // ln2/2
constexpr float EPS_ = 1e-6f;

__device__ __forceinline__ unsigned short f2bf(float f) {
    unsigned int u = __float_as_uint(f);
    u += 0x7FFFu + ((u >> 16) & 1u);          // RNE
    return (unsigned short)(u >> 16);
}
__device__ __forceinline__ unsigned int pkbf(float lo, float hi) {
    __hip_bfloat162 t = __float22bfloat162_rn(float2{lo, hi});
    return *reinterpret_cast<unsigned int*>(&t);
}
__device__ __forceinline__ float fexp2(float x) { return __builtin_amdgcn_exp2f(x); }

#define MFMA(a, b, c) __builtin_amdgcn_mfma_f32_16x16x32_bf16((a), (b), (c), 0, 0, 0)
#define SWZ(byteoff, row) ((byteoff) ^ (((row) & 7) << 4))

// ---------------------------------------------------------------------------
// Phase K — TEMPORAL STREAM SEPARATION. r3-r10 invariant: every variant
// interleaved k-loads and v-loads at instruction granularity (two 64MB
// identically-strided buffers, same row index) and pinned at ~60us / 2TB/s;
// fa_q (one stream, same scatter, same instr count) sustains ~10TB/s.
// Here each 64-row group runs: PASS A = k only (reg dbuf, P-MFMA, E->LDS
// in sigma A-frag halves), sched_barrier, PASS B = v only (reg dbuf,
// sigma-scatter r8-verbatim, EV-MFMA from LDS). Wave-private everything,
// no block barriers; per-wave 64x80 partial (nch = 4*gridX).
// ---------------------------------------------------------------------------
__global__ void __launch_bounds__(256, 2)
fa_k(const float* __restrict__ ks, const float* __restrict__ vs,
     const float* __restrict__ proj, float* __restrict__ partial,
     int nch, int segs)
{
    __shared__ __align__(16) char eL[4 * 8192];  // wave:8K -> p*4096+mt*1024+lane*16+par*8
    __shared__ __align__(16) char vL[4 * 8192];  // wave:8K -> p*4096+c*64+swz(slot)

    const int bh = blockIdx.y;
    const int b = bh >> 3, h = bh & 7;
    const int tid = threadIdx.x, wid = tid >> 6, lane = tid & 63;
    const int l15 = lane & 15, g = lane >> 4;
    const int cw = blockIdx.x * 4 + wid;          // wave-chunk id

    const size_t rs = (size_t)H_ * D_;
    const float* kb = ks + ((size_t)b * S_ * H_ + h) * D_;
    const float* vb = vs + ((size_t)b * S_ * H_ + h) * D_;

    char* eW = eL + wid * 8192;
    char* vW = vL + wid * 8192;

    // proj B-fragments (verified): m = mt*16+l15, d = g*8+j (+32*kk)
    bf16x8 pf[4][2];
#pragma unroll
    for (int mt = 0; mt < 4; ++mt)
#pragma unroll
        for (int kk = 0; kk < 2; ++kk) {
            const float* p = proj + (mt * 16 + l15) * D_ + kk * 32 + g * 8;
            float4 a = *(const float4*)p, c = *(const float4*)(p + 4);
            union { bf16x8 v; unsigned int u[4]; } F;
            F.u[0] = pkbf(a.x, a.y); F.u[1] = pkbf(a.z, a.w);
            F.u[2] = pkbf(c.x, c.y); F.u[3] = pkbf(c.z, c.w);
            pf[mt][kk] = F.v;
        }

    bf16x8 onef = {0, 0, 0, 0, 0, 0, 0, 0};
    if (l15 == 0) {
#pragma unroll
        for (int j = 0; j < 8; ++j) onef[j] = (short)0x3F80;
    }

    f32x4 acc[4][5];
#pragma unroll
    for (int mt = 0; mt < 4; ++mt)
#pragma unroll
        for (int ci = 0; ci < 5; ++ci) acc[mt][ci] = (f32x4){0.f, 0.f, 0.f, 0.f};

// load one 16-row tile of stream BASE into 4 named float4 regs
#define XLOAD(BASE, T, X0, X1, X2, X3) do {                                  \
    const float* r_ = (BASE) + (size_t)(rbase + (T) * 16 + l15) * rs;        \
    X0 = *(const float4*)(r_ + g * 8);                                       \
    X1 = *(const float4*)(r_ + g * 8 + 4);                                   \
    X2 = *(const float4*)(r_ + 32 + g * 8);                                  \
    X3 = *(const float4*)(r_ + 32 + g * 8 + 4);                              \
    } while (0)

// k-tile T -> P-MFMA -> E half (exp2'd, bf16) stored to eW[p][mt][lane][par]
#define CONSK(T, X0, X1, X2, X3) do {                                        \
    float kx_[16];                                                           \
    kx_[0]=X0.x*XS_; kx_[1]=X0.y*XS_; kx_[2]=X0.z*XS_; kx_[3]=X0.w*XS_;      \
    kx_[4]=X1.x*XS_; kx_[5]=X1.y*XS_; kx_[6]=X1.z*XS_; kx_[7]=X1.w*XS_;      \
    kx_[8]=X2.x*XS_; kx_[9]=X2.y*XS_; kx_[10]=X2.z*XS_; kx_[11]=X2.w*XS_;    \
    kx_[12]=X3.x*XS_; kx_[13]=X3.y*XS_; kx_[14]=X3.z*XS_; kx_[15]=X3.w*XS_;  \
    float sq_ = 0.f;                                                         \
    _Pragma("unroll")                                                        \
    for (int j_ = 0; j_ < 16; ++j_) sq_ += kx_[j_] * kx_[j_];                \
    sq_ += __shfl_xor(sq_, 16);                                              \
    sq_ += __shfl_xor(sq_, 32);                                              \
    float hrow_ = sq_ * HS_ + 3.0f;                                          \
    union { bf16x8 v; unsigned int u[4]; } A0_, A1_;                         \
    _Pragma("unroll")                                                        \
    for (int i_ = 0; i_ < 4; ++i_) {                                         \
        A0_.u[i_] = pkbf(kx_[2 * i_], kx_[2 * i_ + 1]);                      \
        A1_.u[i_] = pkbf(kx_[8 + 2 * i_], kx_[9 + 2 * i_]);                  \
    }                                                                        \
    f32x4 pa_[4];                                                            \
    _Pragma("unroll")                                                        \
    for (int mt_ = 0; mt_ < 4; ++mt_) {                                      \
        pa_[mt_] = (f32x4){0.f, 0.f, 0.f, 0.f};                              \
        pa_[mt_] = MFMA(A0_.v, pf[mt_][0], pa_[mt_]);                        \
        pa_[mt_] = MFMA(A1_.v, pf[mt_][1], pa_[mt_]);                        \
    }                                                                        \
    float hr_[4];                                                            \
    _Pragma("unroll")                                                        \
    for (int r_ = 0; r_ < 4; ++r_) hr_[r_] = __shfl(hrow_, 4 * g + r_);      \
    _Pragma("unroll")                                                        \
    for (int mt_ = 0; mt_ < 4; ++mt_) {                                      \
        unsigned int u0_ = pkbf(fexp2(pa_[mt_][0] - hr_[0]),                 \
                                fexp2(pa_[mt_][1] - hr_[1]));                \
        unsigned int u1_ = pkbf(fexp2(pa_[mt_][2] - hr_[2]),                 \
                                fexp2(pa_[mt_][3] - hr_[3]));                \
        *(unsigned long long*)(eW + ((T) >> 1) * 4096 + mt_ * 1024           \
                               + lane * 16 + ((T) & 1) * 8) =                \
            (unsigned long long)u0_ | ((unsigned long long)u1_ << 32);       \
    } } while (0)

// v-tile T -> sigma-scatter into vW[p] (r8-verbatim slot/swizzle)
#define VSCAT(T, X0, X1, X2, X3) do {                                        \
    char* vp_ = vW + ((T) >> 1) * 4096;                                      \
    int slot2_ = 2 * (((l15 >> 2) & 3) * 8 + 4 * ((T) & 1) + (l15 & 3));     \
    float vv_[16];                                                           \
    vv_[0]=X0.x; vv_[1]=X0.y; vv_[2]=X0.z; vv_[3]=X0.w;                      \
    vv_[4]=X1.x; vv_[5]=X1.y; vv_[6]=X1.z; vv_[7]=X1.w;                      \
    vv_[8]=X2.x; vv_[9]=X2.y; vv_[10]=X2.z; vv_[11]=X2.w;                    \
    vv_[12]=X3.x; vv_[13]=X3.y; vv_[14]=X3.z; vv_[15]=X3.w;                  \
    _Pragma("unroll")                                                        \
    for (int p2_ = 0; p2_ < 4; ++p2_) {                                      \
        int cA_ = g * 8 + 2 * p2_;                                           \
        unsigned int pA_ = pkbf(vv_[2 * p2_], vv_[2 * p2_ + 1]);             \
        *(unsigned short*)(vp_ + cA_ * 64 + (slot2_ ^ ((cA_ & 3) << 4))) =   \
            (unsigned short)pA_;                                             \
        int cB_ = cA_ + 1;                                                   \
        *(unsigned short*)(vp_ + cB_ * 64 + (slot2_ ^ ((cB_ & 3) << 4))) =   \
            (unsigned short)(pA_ >> 16);                                     \
        int cC_ = 32 + cA_;                                                  \
        unsigned int pB_ = pkbf(vv_[8 + 2 * p2_], vv_[9 + 2 * p2_]);         \
        *(unsigned short*)(vp_ + cC_ * 64 + (slot2_ ^ ((cC_ & 3) << 4))) =   \
            (unsigned short)pB_;                                             \
        int cD_ = cC_ + 1;                                                   \
        *(unsigned short*)(vp_ + cD_ * 64 + (slot2_ ^ ((cD_ & 3) << 4))) =   \
            (unsigned short)(pB_ >> 16);                                     \
    } } while (0)

// EV over pair P: E from eW (sigma A-layout), V^T B-frags from vW; 20 MFMAs
#define EVP(P) do {                                                          \
    bf16x8 eA_[4], vB_[4];                                                   \
    _Pragma("unroll")                                                        \
    for (int mt_ = 0; mt_ < 4; ++mt_)                                        \
        eA_[mt_] = *(const bf16x8*)(eW + (P) * 4096 + mt_ * 1024             \
                                    + lane * 16);                            \
    _Pragma("unroll")                                                        \
    for (int ct_ = 0; ct_ < 4; ++ct_) {                                      \
        int c_ = ct_ * 16 + l15;                                             \
        vB_[ct_] = *(const bf16x8*)(vW + (P) * 4096 + c_ * 64                \
                                    + ((16 * g) ^ ((c_ & 3) << 4)));         \
    }                                                                        \
    _Pragma("unroll")                                                        \
    for (int mt_ = 0; mt_ < 4; ++mt_) {                                      \
        _Pragma("unroll")                                                    \
        for (int ct_ = 0; ct_ < 4; ++ct_)                                    \
            acc[mt_][ct_] = MFMA(eA_[mt_], vB_[ct_], acc[mt_][ct_]);         \
        acc[mt_][4] = MFMA(eA_[mt_], onef, acc[mt_][4]);                     \
    } } while (0)

    for (int seg = 0; seg < segs; ++seg) {
#pragma unroll
        for (int g2 = 0; g2 < 2; ++g2) {
            const int rbase = cw * (128 * segs) + seg * 128 + g2 * 64;
            float4 a0, a1, a2, a3, b0, b1, b2, b3;

            // ---- PASS A: k stream only ----
            XLOAD(kb, 0, a0, a1, a2, a3);
            XLOAD(kb, 1, b0, b1, b2, b3);
            CONSK(0, a0, a1, a2, a3);
            XLOAD(kb, 2, a0, a1, a2, a3);
            CONSK(1, b0, b1, b2, b3);
            XLOAD(kb, 3, b0, b1, b2, b3);
            CONSK(2, a0, a1, a2, a3);
            CONSK(3, b0, b1, b2, b3);
            __builtin_amdgcn_sched_barrier(0);

            // ---- PASS B: v stream only ----
            XLOAD(vb, 0, a0, a1, a2, a3);
            XLOAD(vb, 1, b0, b1, b2, b3);
            VSCAT(0, a0, a1, a2, a3);
            XLOAD(vb, 2, a0, a1, a2, a3);
            VSCAT(1, b0, b1, b2, b3);
            XLOAD(vb, 3, b0, b1, b2, b3);
            EVP(0);
            VSCAT(2, a0, a1, a2, a3);
            VSCAT(3, b0, b1, b2, b3);
            EVP(1);
            __builtin_amdgcn_sched_barrier(0);
        }
    }

    // wave owns the full 64x80 partial: direct store, no reduce
    float* dst = partial + ((size_t)bh * nch + cw) * MC_;
#pragma unroll
    for (int mt = 0; mt < 4; ++mt)
#pragma unroll
        for (int ct = 0; ct < 5; ++ct)
#pragma unroll
            for (int r = 0; r < 4; ++r)
                dst[(mt * 16 + 4 * g + r) * CPK_ + ct * 16 + l15] =
                    acc[mt][ct][r];
}

// ---------------------------------------------------------------------------
// Reduce partials over chunks -> buf1[bh][m][CPK_]
// ---------------------------------------------------------------------------
__global__ void __launch_bounds__(256)
fa_r(const float* __restrict__ partial, float* __restrict__ buf1, int nch)
{
    int e = blockIdx.x * 256 + threadIdx.x;
    if (e >= BH_ * MC_) return;
    int bh = e / MC_;
    int r  = e - bh * MC_;
    const float* src = partial + (size_t)bh * nch * MC_ + r;
    float s0 = 0.f, s1 = 0.f, s2 = 0.f, s3 = 0.f;
    int ch = 0;
    for (; ch + 4 <= nch; ch += 4) {
        s0 += src[(size_t)(ch + 0) * MC_];
        s1 += src[(size_t)(ch + 1) * MC_];
        s2 += src[(size_t)(ch + 2) * MC_];
        s3 += src[(size_t)(ch + 3) * MC_];
    }
    for (; ch < nch; ++ch) s0 += src[(size_t)ch * MC_];
    buf1[e] = (s0 + s1) + (s2 + s3);
}

// ---------------------------------------------------------------------------
// Phase Q: unchanged (empirically ~10TB/s). P = mfma(Qscaled, projT);
// e = exp2(P-h); D[c][qrow] = mfma(buf1T, E_T); den = c=64 row; out=num/den.
// ---------------------------------------------------------------------------
__global__ void __launch_bounds__(256)
fa_q(const float* __restrict__ qs, const float* __restrict__ proj,
     const float* __restrict__ buf1, float* __restrict__ out)
{
    const int chunk = blockIdx.x;
    const int bh    = blockIdx.y;
    const int b = bh >> 3, h = bh & 7;
    const int tid = threadIdx.x, wid = tid >> 6, lane = tid & 63;
    const int l15 = lane & 15, g = lane >> 4;

    __shared__ __align__(16) char eLb[2][TILE * M_ * 2];
    __shared__ __align__(16) char b1tb[CPK_ * M_ * 2];

    const int rows = S_ / NCHQ;
    const int s0 = chunk * rows;
    const size_t rs = (size_t)H_ * D_;
    const float* qb = qs + ((size_t)b * S_ * H_ + h) * D_;

    const float* b1 = buf1 + (size_t)bh * MC_;
    for (int i = tid; i < MC_; i += 256) {
        int m = i / CPK_, c = i - m * CPK_;
        *(unsigned short*)(b1tb + SWZ(c * 128 + 2 * m, c)) = f2bf(b1[i]);
    }

    bf16x8 pf[4][2];
#pragma unroll
    for (int mt = 0; mt < 4; ++mt)
#pragma unroll
        for (int kk = 0; kk < 2; ++kk) {
            const float* p = proj + (mt * 16 + l15) * D_ + kk * 32 + g * 8;
            float4 a = *(const float4*)p, c = *(const float4*)(p + 4);
            union { bf16x8 v; unsigned int u[4]; } F;
            F.u[0] = pkbf(a.x, a.y); F.u[1] = pkbf(a.z, a.w);
            F.u[2] = pkbf(c.x, c.y); F.u[3] = pkbf(c.z, c.w);
            pf[mt][kk] = F.v;
        }
    __syncthreads();

    bf16x8 af3[5][2];
#pragma unroll
    for (int ci = 0; ci < 5; ++ci)
#pragma unroll
        for (int kk = 0; kk < 2; ++kk) {
            int c = ci * 16 + l15;
            af3[ci][kk] = *(const bf16x8*)(b1tb + SWZ(c * 128 + 16 * g + 64 * kk, c));
        }

    auto loadQ = [&](int t, float4* qp) {
        int sb = s0 + t * TILE;
        const float* qrow = qb + (size_t)(sb + wid * 16 + l15) * rs;
        qp[0] = *(const float4*)(qrow + g * 8);
        qp[1] = *(const float4*)(qrow + g * 8 + 4);
        qp[2] = *(const float4*)(qrow + 32 + g * 8);
        qp[3] = *(const float4*)(qrow + 32 + g * 8 + 4);
    };

    auto body = [&](int t, int p, const float4* qc, float4* qn) {
        if (t + 1 < QTILES) loadQ(t + 1, qn);

        float kx[16];
#pragma unroll
        for (int i = 0; i < 4; ++i) {
            kx[4 * i + 0] = qc[i].x * XS_; kx[4 * i + 1] = qc[i].y * XS_;
            kx[4 * i + 2] = qc[i].z * XS_; kx[4 * i + 3] = qc[i].w * XS_;
        }
        float sq = 0.f;
#pragma unroll
        for (int j = 0; j < 16; ++j) sq += kx[j] * kx[j];
        sq += __shfl_xor(sq, 16);
        sq += __shfl_xor(sq, 32);
        float hrow = sq * HS_ + 3.0f;

        union { bf16x8 v; unsigned int u[4]; } A0, A1;
#pragma unroll
        for (int i = 0; i < 4; ++i) {
            A0.u[i] = pkbf(kx[2 * i], kx[2 * i + 1]);
            A1.u[i] = pkbf(kx[8 + 2 * i], kx[9 + 2 * i]);
        }

        f32x4 pa[4];
#pragma unroll
        for (int mt = 0; mt < 4; ++mt) {
            pa[mt] = (f32x4){0.f, 0.f, 0.f, 0.f};
            pa[mt] = MFMA(A0.v, pf[mt][0], pa[mt]);
            pa[mt] = MFMA(A1.v, pf[mt][1], pa[mt]);
        }

        float hr[4];
#pragma unroll
        for (int r = 0; r < 4; ++r) hr[r] = __shfl(hrow, 4 * g + r);

        char* elp = eLb[p];
#pragma unroll
        for (int mt = 0; mt < 4; ++mt) {
            int m = mt * 16 + l15;
            float e0 = fexp2(pa[mt][0] - hr[0]);
            float e1 = fexp2(pa[mt][1] - hr[1]);
            float e2 = fexp2(pa[mt][2] - hr[2]);
            float e3 = fexp2(pa[mt][3] - hr[3]);
            unsigned int p01 = pkbf(e0, e1), p23 = pkbf(e2, e3);
            int q0 = wid * 16 + 4 * g;
            *(unsigned short*)(elp + SWZ((q0 + 0) * 128 + 2 * m, q0 + 0)) =
                (unsigned short)p01;
            *(unsigned short*)(elp + SWZ((q0 + 1) * 128 + 2 * m, q0 + 1)) =
                (unsigned short)(p01 >> 16);
            *(unsigned short*)(elp + SWZ((q0 + 2) * 128 + 2 * m, q0 + 2)) =
                (unsigned short)p23;
            *(unsigned short*)(elp + SWZ((q0 + 3) * 128 + 2 * m, q0 + 3)) =
                (unsigned short)(p23 >> 16);
        }
        __syncthreads();

        bf16x8 b3[2];
        {
            int qrow = wid * 16 + l15;
            b3[0] = *(const bf16x8*)(elp + SWZ(qrow * 128 + 16 * g, qrow));
            b3[1] = *(const bf16x8*)(elp + SWZ(qrow * 128 + 16 * g + 64, qrow));
        }
        f32x4 dt[5];
#pragma unroll
        for (int ci = 0; ci < 5; ++ci) {
            dt[ci] = (f32x4){0.f, 0.f, 0.f, 0.f};
            dt[ci] = MFMA(af3[ci][0], b3[0], dt[ci]);
            dt[ci] = MFMA(af3[ci][1], b3[1], dt[ci]);
        }

        float den = __shfl(dt[4][0], l15);
        float rd = 1.0f / fmaxf(den, EPS_);

        int sg = s0 + t * TILE + wid * 16 + l15;
        size_t base = (((size_t)b * S_ + sg) * H_ + h) * D_;
#pragma unroll
        for (int ci = 0; ci < 4; ++ci) {
            f32x4 o;
#pragma unroll
            for (int r = 0; r < 4; ++r) o[r] = dt[ci][r] * rd;
            *(f32x4*)(out + base + ci * 16 + 4 * g) = o;
        }
    };

    float4 qa[4], qb2[4];
    loadQ(0, qa);
    for (int t = 0; t < QTILES; t += 2) {
        body(t, 0, qa, qb2);
        body(t + 1, 1, qb2, qa);
    }
}

extern "C" void kernel_launch(void* const* d_in, const int* in_sizes, int n_in,
                              void* d_out, int out_size, void* d_ws, size_t ws_size,
                              hipStream_t stream)
{
    const float* qs   = (const float*)d_in[0];
    const float* ks   = (const float*)d_in[1];
    const float* vs   = (const float*)d_in[2];
    const float* proj = (const float*)d_in[3];
    float* out = (float*)d_out;

    // nch = 64 wave-chunks (gridX=16, segs=1); fallback nch=32 if ws tight
    int segs = 1, nch = 64;
    if ((size_t)BH_ * (size_t)(nch + 1) * MC_ * sizeof(float) > ws_size) {
        segs = 2; nch = 32;
    }
    int gx = 16 / segs;

    float* partial = (float*)d_ws;                // BH*nch*MC_
    float* buf1 = partial + (size_t)BH_ * nch * MC_;

    fa_k<<<dim3(gx, BH_), 256, 0, stream>>>(ks, vs, proj, partial, nch, segs);
    int nred = (BH_ * MC_ + 255) / 256;
    fa_r<<<dim3(nred), 256, 0, stream>>>(partial, buf1, nch);
    fa_q<<<dim3(NCHQ, BH_), 256, 0, stream>>>(qs, proj, buf1, out);
}